// Round 15
// baseline (322.159 us; speedup 1.0000x reference)
//
#include <hip/hip_runtime.h>
#include <hip/hip_bf16.h>

#define DEV __device__ __forceinline__

constexpr int kB = 16, kC = 32, kT = 512, kS = 128, kBC = 512, kLatent = 128;
constexpr float kEps = 1e-8f;

using bf16 = __hip_bfloat16;
using bf16x8 = __attribute__((ext_vector_type(8))) short;
using f32x4  = __attribute__((ext_vector_type(4))) float;

DEV unsigned short f2bf(float v) {
    bf16 h = __float2bfloat16(v);
    return *(unsigned short*)&h;
}

// ---- per-(b,c) downsample + min/max normalize + sqrt term ----
__global__ void gaf_stats_kernel(const float* __restrict__ x_raw,
                                 float* __restrict__ xn, float* __restrict__ sq) {
    int bc = blockIdx.x;
    int s  = threadIdx.x;
    const float* xp = x_raw + (size_t)bc * kT;
    float v = 0.25f * (xp[4*s] + xp[4*s+1] + xp[4*s+2] + xp[4*s+3]);
    __shared__ float smn[kS], smx[kS];
    smn[s] = v; smx[s] = v;
    __syncthreads();
    for (int off = kS/2; off > 0; off >>= 1) {
        if (s < off) {
            smn[s] = fminf(smn[s], smn[s+off]);
            smx[s] = fmaxf(smx[s], smx[s+off]);
        }
        __syncthreads();
    }
    float mn = smn[0], mx = smx[0];
    float xv = 2.0f * (v - mn) / (mx - mn + kEps) - 1.0f;
    xv = fminf(fmaxf(xv, -1.0f), 1.0f);
    float sv = sqrtf(fminf(fmaxf(1.0f - xv*xv, 0.0f), 1.0f));
    xn[bc*kS + s] = xv;
    sq[bc*kS + s] = sv;
}

// ---- all weight transposes in ONE kernel ----
__global__ void wtrans_all_kernel(const float* __restrict__ w1,
                                  const float* __restrict__ w2,
                                  const float* __restrict__ w3,
                                  const float* __restrict__ w4,
                                  bf16* __restrict__ w1b, bf16* __restrict__ wt2,
                                  bf16* __restrict__ wt3, bf16* __restrict__ wt4) {
    int idx = blockIdx.x * blockDim.x + threadIdx.x;
    if (idx < 1024) {
        int oc = idx >> 5, k = idx & 31;
        w1b[idx] = __float2bfloat16(k < 18 ? w1[oc*18 + k] : 0.0f);
        return;
    }
    idx -= 1024;
    const float* src; bf16* dst; int CIN, COUT;
    if (idx < 18432)       { src = w2; dst = wt2; CIN = 32;  COUT = 64;  }
    else if (idx < 92160)  { idx -= 18432;  src = w3; dst = wt3; CIN = 64;  COUT = 128; }
    else if (idx < 387072) { idx -= 92160;  src = w4; dst = wt4; CIN = 128; COUT = 256; }
    else return;
    int ic = idx % CIN;
    int oc = (idx / CIN) % COUT;
    int t  = idx / (CIN * COUT);
    dst[((size_t)t * COUT + oc) * CIN + ic] = __float2bfloat16(src[((size_t)oc * CIN + ic) * 9 + t]);
}

// ---- FUSED conv1+conv2 (unchanged from round 14) ----
__global__ __launch_bounds__(256, 3)
void conv12_kernel(const float* __restrict__ xn, const float* __restrict__ sq,
                   const bf16* __restrict__ w1b, const float* __restrict__ b1,
                   const bf16* __restrict__ wt2, const float* __restrict__ b2,
                   bf16* __restrict__ out, int img0) {
    __shared__ float xl[kS], sl[kS];
    __shared__ __align__(16) union { short G[576][40]; short H[2][288][40]; } U;
    __shared__ __align__(16) short W1s[32][40];

    int tid  = threadIdx.x;
    int lane = tid & 63;
    int wv   = tid >> 6;
    int mblk = blockIdx.x;
    int bz   = blockIdx.y;
    int bc   = img0 + bz;

    if (tid < 128) {
        xl[tid] = xn[(size_t)bc * kS + tid];
        int rr = tid >> 2, sg = tid & 3;
        *(uint4*)&W1s[rr][sg*8] = *(const uint4*)(w1b + rr*32 + sg*8);
    } else {
        sl[tid - 128] = sq[(size_t)bc * kS + (tid - 128)];
    }
    __syncthreads();

    #pragma unroll
    for (int it = 0; it < 3; ++it) {
        int idx = it * 256 + tid;
        if (idx >= 576) break;
        int trow = idx >> 6, hx = idx & 63;
        int iy = 8 * mblk + trow;
        unsigned int pk[16];
        #pragma unroll
        for (int j = 0; j < 16; ++j) pk[j] = 0u;
        if (iy < 64) {
            float xr[3], sr[3], xc[3], sc[3];
            #pragma unroll
            for (int k = 0; k < 3; ++k) {
                int iyy = 2*iy + k, ixx = 2*hx + k;
                bool vy = iyy < kS, vx = ixx < kS;
                xr[k] = vy ? xl[iyy] : 0.0f;  sr[k] = vy ? sl[iyy] : 0.0f;
                xc[k] = vx ? xl[ixx] : 0.0f;  sc[k] = vx ? sl[ixx] : 0.0f;
            }
            unsigned short gs[18];
            #pragma unroll
            for (int ky = 0; ky < 3; ++ky)
                #pragma unroll
                for (int kx = 0; kx < 3; ++kx) {
                    gs[ky*3+kx]   = f2bf(xr[ky]*xc[kx] - sr[ky]*sc[kx]);
                    gs[9+ky*3+kx] = f2bf(sr[ky]*xc[kx] - xr[ky]*sc[kx]);
                }
            #pragma unroll
            for (int j = 0; j < 9; ++j)
                pk[j] = (unsigned int)gs[2*j] | ((unsigned int)gs[2*j+1] << 16);
        }
        #pragma unroll
        for (int j = 0; j < 4; ++j) *(uint4*)&U.G[idx][j*8] = ((uint4*)pk)[j];
    }
    __syncthreads();

    f32x4 c1[9][2];
    bf16x8 w1f0 = *(const bf16x8*)&W1s[(lane & 15)][(lane>>4)*8];
    bf16x8 w1f1 = *(const bf16x8*)&W1s[16 + (lane & 15)][(lane>>4)*8];
    #pragma unroll
    for (int j = 0; j < 9; ++j) {
        int mt = 4*j + wv;
        bf16x8 af = *(const bf16x8*)&U.G[mt*16 + (lane & 15)][(lane>>4)*8];
        f32x4 zz = f32x4{0.f, 0.f, 0.f, 0.f};
        c1[j][0] = __builtin_amdgcn_mfma_f32_16x16x32_bf16(af, w1f0, zz, 0, 0, 0);
        c1[j][1] = __builtin_amdgcn_mfma_f32_16x16x32_bf16(af, w1f1, zz, 0, 0, 0);
    }
    __syncthreads();

    #pragma unroll
    for (int j = 0; j < 9; ++j) {
        int mt = 4*j + wv;
        #pragma unroll
        for (int h = 0; h < 2; ++h) {
            int oc = h*16 + (lane & 15);
            float bb = b1[oc];
            #pragma unroll
            for (int rg = 0; rg < 4; ++rg) {
                int pos = mt*16 + (lane>>4)*4 + rg;
                int trow = pos >> 6, hx = pos & 63;
                float v = fmaxf(c1[j][h][rg] + bb, 0.0f);
                if (8*mblk + trow >= 64) v = 0.0f;
                U.H[hx & 1][trow*32 + (hx >> 1)][oc] = (short)f2bf(v);
            }
        }
    }
    __syncthreads();

    auto loadB2 = [&](int tap, bf16x8* dst) {
        #pragma unroll
        for (int ni = 0; ni < 4; ++ni) {
            int row = ni*16 + (lane & 15);
            dst[ni] = *(const bf16x8*)(wt2 + ((size_t)tap*64 + row)*32 + (lane>>4)*8);
        }
    };
    f32x4 acc[2][4];
    #pragma unroll
    for (int i = 0; i < 2; ++i)
        #pragma unroll
        for (int j = 0; j < 4; ++j) acc[i][j] = f32x4{0.f, 0.f, 0.f, 0.f};

    bf16x8 bcur[4], bnxt[4];
    loadB2(0, bcur);
    for (int tap = 0; tap < 9; ++tap) {
        if (tap + 1 < 9) loadB2(tap + 1, bnxt);
        int ky = tap / 3, kx = tap % 3;
        int trow = 2*wv + ky;
        bf16x8 af[2];
        #pragma unroll
        for (int mi = 0; mi < 2; ++mi) {
            int ocol = mi*16 + (lane & 15);
            int x = 2*ocol + kx;
            bf16x8 z = {0,0,0,0,0,0,0,0};
            af[mi] = (x < 64) ? *(const bf16x8*)&U.H[kx & 1][trow*32 + (x>>1)][(lane>>4)*8] : z;
        }
        #pragma unroll
        for (int mi = 0; mi < 2; ++mi)
            #pragma unroll
            for (int ni = 0; ni < 4; ++ni)
                acc[mi][ni] = __builtin_amdgcn_mfma_f32_16x16x32_bf16(af[mi], bcur[ni], acc[mi][ni], 0, 0, 0);
        #pragma unroll
        for (int ni = 0; ni < 4; ++ni) bcur[ni] = bnxt[ni];
    }

    int oy = 4*mblk + wv;
    #pragma unroll
    for (int ni = 0; ni < 4; ++ni) {
        int oc = ni*16 + (lane & 15);
        float b = b2[oc];
        #pragma unroll
        for (int mi = 0; mi < 2; ++mi)
            #pragma unroll
            for (int rg = 0; rg < 4; ++rg) {
                int ocol = 16*mi + (lane>>4)*4 + rg;
                float v = fmaxf(acc[mi][ni][rg] + b, 0.0f);
                out[(((size_t)bz*32 + oy)*32 + ocol)*64 + oc] = __float2bfloat16(v);
            }
    }
}

// ---- conv3: window-resident per-ic-slice, barrier-light, B direct ----
// Block = 4 out rows x 16 cols (M=64) x N=128 (all oc). 4 waves (wm,wn): wave
// 32M x 64N, acc[2][4]. Window per slice: [par2][r9][colx16][slot4][8] = 18 KiB,
// slot = icq ^ ((colx>>2)&3) (2-way-free reads). 2 slices -> 4 barriers total.
// B fragments straight from wt3 (L2) with distance-1 register prefetch.
__global__ __launch_bounds__(256, 4)
void conv3_kernel(const bf16* __restrict__ h2, const bf16* __restrict__ wt3,
                  const float* __restrict__ b3, bf16* __restrict__ h3) {
    __shared__ __align__(16) short Win[9216];   // 18 KiB

    int tid  = threadIdx.x;
    int lane = tid & 63;
    int wv   = tid >> 6;
    int wm   = wv >> 1, wn = wv & 1;
    int mblk = blockIdx.x;      // 0..3 -> out rows 4*mblk..4*mblk+3
    int img  = blockIdx.y;
    const bf16* h2i = h2 + (size_t)img * 65536;

    f32x4 acc[2][4];
    #pragma unroll
    for (int i = 0; i < 2; ++i)
        #pragma unroll
        for (int j = 0; j < 4; ++j) acc[i][j] = f32x4{0.f,0.f,0.f,0.f};

    auto loadB = [&](int s, bf16x8* d) {
        int ich = s / 9, tap = s % 9;
        #pragma unroll
        for (int ni = 0; ni < 4; ++ni) {
            int row = wn*64 + ni*16 + (lane & 15);
            d[ni] = *(const bf16x8*)(wt3 + ((size_t)tap*128 + row)*64 + ich*32 + (lane>>4)*8);
        }
    };

    bf16x8 bcur[4], bnxt[4];
    loadB(0, bcur);

    for (int ich = 0; ich < 2; ++ich) {
        if (ich) __syncthreads();           // window reads of prev slice done
        // stage window slice (1152 uint4)
        #pragma unroll
        for (int it = 0; it < 5; ++it) {
            int o = it*256 + tid;
            if (o < 1152) {
                int icq = o & 3, colx = (o>>2) & 15, pr = o >> 6;
                int r = pr % 9, par = pr / 9;
                int gr = mblk*8 + r;
                int ix = colx*2 + par;
                uint4 v = {0u,0u,0u,0u};
                if (gr < 32) v = *(const uint4*)(h2i + ((size_t)gr*32 + ix)*64 + ich*32 + icq*8);
                *(uint4*)&Win[(((par*9 + r)*16 + colx)*4 + (icq ^ ((colx>>2)&3)))*8] = v;
            }
        }
        __syncthreads();

        for (int tap = 0; tap < 9; ++tap) {
            int s = ich*9 + tap;
            if (s + 1 < 18) loadB(s + 1, bnxt);
            int ky = tap/3, kx = tap%3;
            bf16x8 af[2];
            #pragma unroll
            for (int mi = 0; mi < 2; ++mi) {
                int m = wm*32 + mi*16 + (lane & 15);
                int oyl = m >> 4, ox3 = m & 15;
                int iy = 2*oyl + ky, ix = 2*ox3 + kx;
                int par = ix & 1, colx = ix >> 1;
                int colc = colx > 15 ? 15 : colx;
                bf16x8 v = *(const bf16x8*)&Win[(((par*9 + iy)*16 + colc)*4 + ((lane>>4) ^ ((colc>>2)&3)))*8];
                bf16x8 z = {0,0,0,0,0,0,0,0};
                af[mi] = (ix < 32) ? v : z;
            }
            #pragma unroll
            for (int mi = 0; mi < 2; ++mi)
                #pragma unroll
                for (int ni = 0; ni < 4; ++ni)
                    acc[mi][ni] = __builtin_amdgcn_mfma_f32_16x16x32_bf16(af[mi], bcur[ni], acc[mi][ni], 0, 0, 0);
            #pragma unroll
            for (int ni = 0; ni < 4; ++ni) bcur[ni] = bnxt[ni];
        }
    }

    // epilogue: h3 NHWC [img][16][16][128]
    #pragma unroll
    for (int ni = 0; ni < 4; ++ni) {
        int oc = wn*64 + ni*16 + (lane & 15);
        float bb = b3[oc];
        #pragma unroll
        for (int mi = 0; mi < 2; ++mi)
            #pragma unroll
            for (int rg = 0; rg < 4; ++rg) {
                int m = wm*32 + mi*16 + (lane>>4)*4 + rg;
                int oyl = m >> 4, ox3 = m & 15;
                int oye = mblk*4 + oyl;
                float v = fmaxf(acc[mi][ni][rg] + bb, 0.0f);
                h3[(((size_t)img*16 + oye)*16 + ox3)*128 + oc] = __float2bfloat16(v);
            }
    }
}

// ---- conv4: window-resident per-ic-slice (16 KiB), barrier-light, B direct.
// Block = 1 image (M=64) x N=128 (nblk). 4 waves (wm,wn): wave 32M x 64N,
// acc[2][4]. Window: [par2][iy16][col8][slot4][8], slot = icq^((col+(iy>>1))&3)
// (2-way-free). 4 slices -> 8 barriers. Fused global-avg-pool epilogue. ----
__global__ __launch_bounds__(256, 4)
void conv4_kernel(const bf16* __restrict__ h3, const bf16* __restrict__ wt4,
                  const float* __restrict__ b4, float* __restrict__ pooled,
                  int img0) {
    __shared__ __align__(16) short Win[8192];    // 16 KiB
    __shared__ float partial[2][128];

    int tid  = threadIdx.x;
    int lane = tid & 63;
    int wv   = tid >> 6;
    int wm   = wv >> 1, wn = wv & 1;
    int nblk = blockIdx.x;      // oc half (0:0-127, 1:128-255)
    int img  = blockIdx.y;
    const bf16* h3i = h3 + (size_t)img * 32768;

    f32x4 acc[2][4];
    #pragma unroll
    for (int i = 0; i < 2; ++i)
        #pragma unroll
        for (int j = 0; j < 4; ++j) acc[i][j] = f32x4{0.f,0.f,0.f,0.f};

    auto loadB = [&](int s, bf16x8* d) {
        int sl = s / 9, tap = s % 9;
        #pragma unroll
        for (int ni = 0; ni < 4; ++ni) {
            int row = nblk*128 + wn*64 + ni*16 + (lane & 15);
            d[ni] = *(const bf16x8*)(wt4 + ((size_t)tap*256 + row)*128 + sl*32 + (lane>>4)*8);
        }
    };

    bf16x8 bcur[4], bnxt[4];
    loadB(0, bcur);

    for (int sl = 0; sl < 4; ++sl) {
        if (sl) __syncthreads();
        // stage window slice (2048 uint4)
        #pragma unroll
        for (int it = 0; it < 8; ++it) {
            int o = it*256 + tid;
            int icq = o & 3, col = (o>>2) & 7, iy = (o>>5) & 15, par = o >> 9;
            int ix = col*2 + par;
            uint4 v = *(const uint4*)(h3i + ((size_t)iy*16 + ix)*128 + sl*32 + icq*8);
            *(uint4*)&Win[(((par*16 + iy)*8 + col)*4 + (icq ^ ((col + (iy>>1)) & 3)))*8] = v;
        }
        __syncthreads();

        for (int tap = 0; tap < 9; ++tap) {
            int s = sl*9 + tap;
            if (s + 1 < 36) loadB(s + 1, bnxt);
            int ky = tap/3, kx = tap%3;
            bf16x8 af[2];
            #pragma unroll
            for (int mi = 0; mi < 2; ++mi) {
                int m = wm*32 + mi*16 + (lane & 15);
                int oy = m >> 3, ox = m & 7;
                int iy = 2*oy + ky, ix = 2*ox + kx;
                bool valid = (iy < 16) && (ix < 16);
                int iyc = iy > 15 ? 15 : iy, ixc = ix > 15 ? 15 : ix;
                int par = ixc & 1, col = ixc >> 1;
                bf16x8 v = *(const bf16x8*)&Win[(((par*16 + iyc)*8 + col)*4 + ((lane>>4) ^ ((col + (iyc>>1)) & 3)))*8];
                bf16x8 z = {0,0,0,0,0,0,0,0};
                af[mi] = valid ? v : z;
            }
            #pragma unroll
            for (int mi = 0; mi < 2; ++mi)
                #pragma unroll
                for (int ni = 0; ni < 4; ++ni)
                    acc[mi][ni] = __builtin_amdgcn_mfma_f32_16x16x32_bf16(af[mi], bcur[ni], acc[mi][ni], 0, 0, 0);
            #pragma unroll
            for (int ni = 0; ni < 4; ++ni) bcur[ni] = bnxt[ni];
        }
    }

    // fused global-avg-pool: relu+bias, sum wave-local 32 rows, fold lanes,
    // combine the two wm halves via LDS.
    #pragma unroll
    for (int ni = 0; ni < 4; ++ni) {
        int oc = nblk*128 + wn*64 + ni*16 + (lane & 15);
        float bb = b4[oc];
        float ssum = 0.0f;
        #pragma unroll
        for (int mi = 0; mi < 2; ++mi)
            #pragma unroll
            for (int rg = 0; rg < 4; ++rg) ssum += fmaxf(acc[mi][ni][rg] + bb, 0.0f);
        ssum += __shfl_xor(ssum, 16);
        ssum += __shfl_xor(ssum, 32);
        if (lane < 16) partial[wm][wn*64 + ni*16 + lane] = ssum;
    }
    __syncthreads();
    if (tid < 128) {
        float v = partial[0][tid] + partial[1][tid];
        pooled[((size_t)(img0 + img))*256 + nblk*128 + tid] = v * (1.0f/64.0f);
    }
}

// ---- fused: mean over C (commutes with linear FC) + FC 256->128 ----
__global__ void poolfc_kernel(const float* __restrict__ pooled, const float* __restrict__ Wfc,
                              const float* __restrict__ bfc, float* __restrict__ out) {
    int b = blockIdx.x;
    int t = threadIdx.x;
    __shared__ float pm[256];
    #pragma unroll
    for (int q = 0; q < 2; ++q) {
        int k = q*128 + t;
        float s = 0.0f;
        #pragma unroll
        for (int c = 0; c < kC; ++c) s += pooled[((size_t)(b*kC + c))*256 + k];
        pm[k] = s * (1.0f/kC);
    }
    __syncthreads();
    float acc = bfc[t];
    for (int k = 0; k < 256; ++k) acc = fmaf(pm[k], Wfc[(size_t)k*kLatent + t], acc);
    out[(size_t)b*kLatent + t] = acc;
}

extern "C" void kernel_launch(void* const* d_in, const int* in_sizes, int n_in,
                              void* d_out, int out_size, void* d_ws, size_t ws_size,
                              hipStream_t stream) {
    const float* x_raw = (const float*)d_in[0];
    const float* W1 = (const float*)d_in[1];  const float* b1 = (const float*)d_in[2];
    const float* W2 = (const float*)d_in[3];  const float* b2 = (const float*)d_in[4];
    const float* W3 = (const float*)d_in[5];  const float* b3 = (const float*)d_in[6];
    const float* W4 = (const float*)d_in[7];  const float* b4 = (const float*)d_in[8];
    const float* Wfc = (const float*)d_in[9]; const float* bfc = (const float*)d_in[10];
    float* out = (float*)d_out;

    char* wsb = (char*)d_ws;
    float* xn     = (float*)(wsb);                      // 256 KiB
    float* sq     = (float*)(wsb + (256u<<10));         // 256 KiB
    float* pooled = (float*)(wsb + (512u<<10));         // 512 KiB
    bf16* Wt2     = (bf16*)(wsb + (1280u<<10));         // 36 KiB
    bf16* Wt3     = (bf16*)(wsb + (1316u<<10));         // 144 KiB
    bf16* Wt4     = (bf16*)(wsb + (1460u<<10));         // 576 KiB
    bf16* W1b     = (bf16*)(wsb + (2036u<<10));         // 2 KiB
    char* chunk_base = wsb + (2048u<<10);               // 2 MiB header

    // per image: h2 NHWC (128 KiB) + h3 NHWC (64 KiB)
    const size_t perH2 = 32u*32u*64u*2u, perH3 = 16u*16u*128u*2u;
    const size_t perImg = perH2 + perH3;
    int chunk = 4;
    for (int c = 512; c >= 4; c >>= 1) {
        if ((2048u<<10) + (size_t)c * perImg <= ws_size) { chunk = c; break; }
    }

    gaf_stats_kernel<<<kBC, kS, 0, stream>>>(x_raw, xn, sq);
    wtrans_all_kernel<<<(388096 + 255)/256, 256, 0, stream>>>(W1, W2, W3, W4, W1b, Wt2, Wt3, Wt4);

    for (int img0 = 0; img0 < kBC; img0 += chunk) {
        int nimg = chunk;
        bf16* h2 = (bf16*)chunk_base;
        bf16* h3 = (bf16*)(chunk_base + (size_t)chunk * perH2);

        // fused conv1+conv2: 2->32->64, 128->64->32
        conv12_kernel<<<dim3(8, nimg), 256, 0, stream>>>(xn, sq, W1b, b1, Wt2, b2, h2, img0);
        // conv3: 64->128, 32->16 : 4 mblk x img, window-resident
        conv3_kernel<<<dim3(4, nimg), 256, 0, stream>>>(h2, Wt3, b3, h3);
        // conv4: 128->256, 16->8 : 2 nblk x img, window-resident, fused pool
        conv4_kernel<<<dim3(2, nimg), 256, 0, stream>>>(h3, Wt4, b4, pooled, img0);
    }

    poolfc_kernel<<<kB, kLatent, 0, stream>>>(pooled, Wfc, bfc, out);
}

// Round 16
// 214.433 us; speedup vs baseline: 1.5024x; 1.5024x over previous
//
#include <hip/hip_runtime.h>
#include <hip/hip_bf16.h>

#define DEV __device__ __forceinline__

constexpr int kB = 16, kC = 32, kT = 512, kS = 128, kBC = 512, kLatent = 128;
constexpr float kEps = 1e-8f;

using bf16 = __hip_bfloat16;
using bf16x8 = __attribute__((ext_vector_type(8))) short;
using f32x4  = __attribute__((ext_vector_type(4))) float;

DEV unsigned short f2bf(float v) {
    bf16 h = __float2bfloat16(v);
    return *(unsigned short*)&h;
}

DEV void gld16(const void* g, void* l) {
    __builtin_amdgcn_global_load_lds(
        (const __attribute__((address_space(1))) unsigned*)g,
        (__attribute__((address_space(3))) unsigned*)l, 16, 0, 0);
}

// ---- per-(b,c) downsample + min/max normalize + sqrt term ----
__global__ void gaf_stats_kernel(const float* __restrict__ x_raw,
                                 float* __restrict__ xn, float* __restrict__ sq) {
    int bc = blockIdx.x;
    int s  = threadIdx.x;
    const float* xp = x_raw + (size_t)bc * kT;
    float v = 0.25f * (xp[4*s] + xp[4*s+1] + xp[4*s+2] + xp[4*s+3]);
    __shared__ float smn[kS], smx[kS];
    smn[s] = v; smx[s] = v;
    __syncthreads();
    for (int off = kS/2; off > 0; off >>= 1) {
        if (s < off) {
            smn[s] = fminf(smn[s], smn[s+off]);
            smx[s] = fmaxf(smx[s], smx[s+off]);
        }
        __syncthreads();
    }
    float mn = smn[0], mx = smx[0];
    float xv = 2.0f * (v - mn) / (mx - mn + kEps) - 1.0f;
    xv = fminf(fmaxf(xv, -1.0f), 1.0f);
    float sv = sqrtf(fminf(fmaxf(1.0f - xv*xv, 0.0f), 1.0f));
    xn[bc*kS + s] = xv;
    sq[bc*kS + s] = sv;
}

// ---- all weight transposes in ONE kernel ----
__global__ void wtrans_all_kernel(const float* __restrict__ w1,
                                  const float* __restrict__ w2,
                                  const float* __restrict__ w3,
                                  const float* __restrict__ w4,
                                  bf16* __restrict__ w1b, bf16* __restrict__ wt2,
                                  bf16* __restrict__ wt3, bf16* __restrict__ wt4) {
    int idx = blockIdx.x * blockDim.x + threadIdx.x;
    if (idx < 1024) {
        int oc = idx >> 5, k = idx & 31;
        w1b[idx] = __float2bfloat16(k < 18 ? w1[oc*18 + k] : 0.0f);
        return;
    }
    idx -= 1024;
    const float* src; bf16* dst; int CIN, COUT;
    if (idx < 18432)       { src = w2; dst = wt2; CIN = 32;  COUT = 64;  }
    else if (idx < 92160)  { idx -= 18432;  src = w3; dst = wt3; CIN = 64;  COUT = 128; }
    else if (idx < 387072) { idx -= 92160;  src = w4; dst = wt4; CIN = 128; COUT = 256; }
    else return;
    int ic = idx % CIN;
    int oc = (idx / CIN) % COUT;
    int t  = idx / (CIN * COUT);
    dst[((size_t)t * COUT + oc) * CIN + ic] = __float2bfloat16(src[((size_t)oc * CIN + ic) * 9 + t]);
}

// ---- FUSED conv1+conv2 ----
// Round-14 structure; G/H repacked to 32-short rows with XOR slot swizzle
// (slot_phys = slot_logical ^ (row&3)) -> 2-way-free LDS accesses with ZERO
// row padding. LDS 39.5 KiB -> 4 blocks/CU.
__global__ __launch_bounds__(256, 4)
void conv12_kernel(const float* __restrict__ xn, const float* __restrict__ sq,
                   const bf16* __restrict__ w1b, const float* __restrict__ b1,
                   const bf16* __restrict__ wt2, const float* __restrict__ b2,
                   bf16* __restrict__ out, int img0) {
    __shared__ float xl[kS], sl[kS];
    __shared__ __align__(16) short GH[18432];    // 36 KiB: G[576][4][8] / H[2][288][4][8]
    __shared__ __align__(16) short W1s[32][40];  // 2.5 KiB

    int tid  = threadIdx.x;
    int lane = tid & 63;
    int wv   = tid >> 6;
    int mblk = blockIdx.x;
    int bz   = blockIdx.y;
    int bc   = img0 + bz;

    if (tid < 128) {
        xl[tid] = xn[(size_t)bc * kS + tid];
        int rr = tid >> 2, sg = tid & 3;
        *(uint4*)&W1s[rr][sg*8] = *(const uint4*)(w1b + rr*32 + sg*8);
    } else {
        sl[tid - 128] = sq[(size_t)bc * kS + (tid - 128)];
    }
    __syncthreads();

    // ---- Phase 1a: G (swizzled slots) ----
    #pragma unroll
    for (int it = 0; it < 3; ++it) {
        int idx = it * 256 + tid;
        if (idx >= 576) break;
        int trow = idx >> 6, hx = idx & 63;
        int iy = 8 * mblk + trow;
        unsigned int pk[16];
        #pragma unroll
        for (int j = 0; j < 16; ++j) pk[j] = 0u;
        if (iy < 64) {
            float xr[3], sr[3], xc[3], sc[3];
            #pragma unroll
            for (int k = 0; k < 3; ++k) {
                int iyy = 2*iy + k, ixx = 2*hx + k;
                bool vy = iyy < kS, vx = ixx < kS;
                xr[k] = vy ? xl[iyy] : 0.0f;  sr[k] = vy ? sl[iyy] : 0.0f;
                xc[k] = vx ? xl[ixx] : 0.0f;  sc[k] = vx ? sl[ixx] : 0.0f;
            }
            unsigned short gs[18];
            #pragma unroll
            for (int ky = 0; ky < 3; ++ky)
                #pragma unroll
                for (int kx = 0; kx < 3; ++kx) {
                    gs[ky*3+kx]   = f2bf(xr[ky]*xc[kx] - sr[ky]*sc[kx]);
                    gs[9+ky*3+kx] = f2bf(sr[ky]*xc[kx] - xr[ky]*sc[kx]);
                }
            #pragma unroll
            for (int j = 0; j < 9; ++j)
                pk[j] = (unsigned int)gs[2*j] | ((unsigned int)gs[2*j+1] << 16);
        }
        #pragma unroll
        for (int j = 0; j < 4; ++j)
            *(uint4*)&GH[idx*32 + ((j ^ (idx & 3)) * 8)] = ((uint4*)pk)[j];
    }
    __syncthreads();

    // ---- Phase 1b: h1 = relu(G @ W1b^T + b1) ----
    f32x4 c1[9][2];
    bf16x8 w1f0 = *(const bf16x8*)&W1s[(lane & 15)][(lane>>4)*8];
    bf16x8 w1f1 = *(const bf16x8*)&W1s[16 + (lane & 15)][(lane>>4)*8];
    #pragma unroll
    for (int j = 0; j < 9; ++j) {
        int mt = 4*j + wv;
        int row = mt*16 + (lane & 15);
        bf16x8 af = *(const bf16x8*)&GH[row*32 + (((lane>>4) ^ (row & 3)) * 8)];
        f32x4 zz = f32x4{0.f, 0.f, 0.f, 0.f};
        c1[j][0] = __builtin_amdgcn_mfma_f32_16x16x32_bf16(af, w1f0, zz, 0, 0, 0);
        c1[j][1] = __builtin_amdgcn_mfma_f32_16x16x32_bf16(af, w1f1, zz, 0, 0, 0);
    }
    __syncthreads();   // all G reads complete before overwrite

    #pragma unroll
    for (int j = 0; j < 9; ++j) {
        int mt = 4*j + wv;
        #pragma unroll
        for (int h = 0; h < 2; ++h) {
            int oc = h*16 + (lane & 15);
            float bb = b1[oc];
            #pragma unroll
            for (int rg = 0; rg < 4; ++rg) {
                int pos = mt*16 + (lane>>4)*4 + rg;
                int trow = pos >> 6, hx = pos & 63;
                int par = hx & 1, col = hx >> 1;
                int r = trow*32 + col;
                float v = fmaxf(c1[j][h][rg] + bb, 0.0f);
                if (8*mblk + trow >= 64) v = 0.0f;   // SAME padding row
                GH[par*9216 + r*32 + (((oc>>3) ^ (r & 3)) * 8) + (oc & 7)] = (short)f2bf(v);
            }
        }
    }
    __syncthreads();

    // ---- Phase 2: conv2 GEMM, barrier-free (B direct from global) ----
    auto loadB2 = [&](int tap, bf16x8* dst) {
        #pragma unroll
        for (int ni = 0; ni < 4; ++ni) {
            int row = ni*16 + (lane & 15);
            dst[ni] = *(const bf16x8*)(wt2 + ((size_t)tap*64 + row)*32 + (lane>>4)*8);
        }
    };
    f32x4 acc[2][4];
    #pragma unroll
    for (int i = 0; i < 2; ++i)
        #pragma unroll
        for (int j = 0; j < 4; ++j) acc[i][j] = f32x4{0.f, 0.f, 0.f, 0.f};

    bf16x8 bcur[4], bnxt[4];
    loadB2(0, bcur);
    for (int tap = 0; tap < 9; ++tap) {
        if (tap + 1 < 9) loadB2(tap + 1, bnxt);
        int ky = tap / 3, kx = tap % 3;
        int trow = 2*wv + ky;
        bf16x8 af[2];
        #pragma unroll
        for (int mi = 0; mi < 2; ++mi) {
            int ocol = mi*16 + (lane & 15);
            int x = 2*ocol + kx;
            int par = x & 1;
            int col = x >> 1; if (col > 31) col = 31;
            int r = trow*32 + col;
            bf16x8 v = *(const bf16x8*)&GH[par*9216 + r*32 + (((lane>>4) ^ (r & 3)) * 8)];
            bf16x8 z = {0,0,0,0,0,0,0,0};
            af[mi] = (x < 64) ? v : z;
        }
        #pragma unroll
        for (int mi = 0; mi < 2; ++mi)
            #pragma unroll
            for (int ni = 0; ni < 4; ++ni)
                acc[mi][ni] = __builtin_amdgcn_mfma_f32_16x16x32_bf16(af[mi], bcur[ni], acc[mi][ni], 0, 0, 0);
        #pragma unroll
        for (int ni = 0; ni < 4; ++ni) bcur[ni] = bnxt[ni];
    }

    int oy = 4*mblk + wv;
    #pragma unroll
    for (int ni = 0; ni < 4; ++ni) {
        int oc = ni*16 + (lane & 15);
        float b = b2[oc];
        #pragma unroll
        for (int mi = 0; mi < 2; ++mi)
            #pragma unroll
            for (int rg = 0; rg < 4; ++rg) {
                int ocol = 16*mi + (lane>>4)*4 + rg;
                float v = fmaxf(acc[mi][ni][rg] + b, 0.0f);
                out[(((size_t)bz*32 + oy)*32 + ocol)*64 + oc] = __float2bfloat16(v);
            }
    }
}

// ---- MFMA implicit-GEMM conv (round-14: gld16 streaming, IC-MAJOR K) ----
// Block 128M x 128N, 2x2 waves (wave 64x64, acc 4x4), BK=32 double-buffered
// gld16 staging, 1 barrier/stage. K = (icb OUTER, tap INNER): taps innermost
// re-read the same pixel window -> L1/L2-hot re-stages, ~1/9 tap-major HBM.
template<int CIN, int COUT, int HIN, int IMGS, bool POOL>
__global__ __launch_bounds__(256, 4)
void conv_mfma_kernel(const bf16* __restrict__ in, const bf16* __restrict__ wt,
                      const float* __restrict__ bias, bf16* __restrict__ out,
                      float* __restrict__ pooled, int img0,
                      const bf16* __restrict__ zbuf) {
    constexpr int HOUT = HIN / 2;
    constexpr int PPI  = HOUT * HOUT;
    constexpr int S    = 9 * (CIN / 32);
    __shared__ __align__(16) short As[2*128*32];   // 16 KiB
    __shared__ __align__(16) short Bs[2*128*32];   // 16 KiB

    int tid  = threadIdx.x;
    int lane = tid & 63;
    int wv   = tid >> 6;
    int wm   = wv >> 1, wn = wv & 1;
    int bx   = blockIdx.x;
    int nblk = blockIdx.y;
    int bz   = blockIdx.z;

    int rsub = lane >> 2, seg = lane & 3;
    int imgA[2], oyA[2], oxA[2], rB[2];
    #pragma unroll
    for (int j = 0; j < 2; ++j) {
        int r = (wv*2 + j)*16 + rsub;       // 0..127
        int il, pos;
        if (IMGS > 1) { il = bz*IMGS + r/PPI; pos = r % PPI; }
        else          { il = bz; pos = bx*128 + r; }
        imgA[j] = il; oyA[j] = pos / HOUT; oxA[j] = pos % HOUT;
        rB[j] = r;
    }

    auto issue = [&](int s, int nb) {
        int icb = (s / 9) * 32;            // ic-major
        int tap = s % 9;                   // taps innermost -> window reuse
        int ky = tap / 3, kx = tap % 3;
        #pragma unroll
        for (int j = 0; j < 2; ++j) {
            int iy = 2*oyA[j] + ky, ix = 2*oxA[j] + kx;
            const bf16* ga = (iy < HIN && ix < HIN)
                ? in + (((size_t)imgA[j]*HIN + iy)*HIN + ix)*CIN + icb + seg*8
                : zbuf + seg*8;
            gld16(ga, (char*)As + nb*8192 + (wv*2 + j)*1024 + lane*16);
            const bf16* gb = wt + ((size_t)tap*COUT + nblk*128 + rB[j])*CIN + icb + seg*8;
            gld16(gb, (char*)Bs + nb*8192 + (wv*2 + j)*1024 + lane*16);
        }
    };

    f32x4 acc[4][4];
    #pragma unroll
    for (int i = 0; i < 4; ++i)
        #pragma unroll
        for (int j = 0; j < 4; ++j) acc[i][j] = f32x4{0.f, 0.f, 0.f, 0.f};

    issue(0, 0);
    __syncthreads();

    for (int s = 0; s < S; ++s) {
        int cur = s & 1;
        if (s + 1 < S) issue(s + 1, cur ^ 1);
        bf16x8 af[4], bfr[4];
        #pragma unroll
        for (int mi = 0; mi < 4; ++mi)
            af[mi] = *(const bf16x8*)&As[cur*4096 + (wm*64 + mi*16 + (lane&15))*32 + (lane>>4)*8];
        #pragma unroll
        for (int ni = 0; ni < 4; ++ni)
            bfr[ni] = *(const bf16x8*)&Bs[cur*4096 + (wn*64 + ni*16 + (lane&15))*32 + (lane>>4)*8];
        #pragma unroll
        for (int mi = 0; mi < 4; ++mi)
            #pragma unroll
            for (int ni = 0; ni < 4; ++ni)
                acc[mi][ni] = __builtin_amdgcn_mfma_f32_16x16x32_bf16(af[mi], bfr[ni], acc[mi][ni], 0, 0, 0);
        __syncthreads();
    }

    if (!POOL) {
        #pragma unroll
        for (int ni = 0; ni < 4; ++ni) {
            int oc = nblk*128 + wn*64 + ni*16 + (lane & 15);
            float b = bias[oc];
            #pragma unroll
            for (int mi = 0; mi < 4; ++mi)
                #pragma unroll
                for (int rg = 0; rg < 4; ++rg) {
                    int rr = wm*64 + mi*16 + (lane>>4)*4 + rg;
                    int img_e, pos_e;
                    if (IMGS > 1) { img_e = bz*IMGS + rr/PPI; pos_e = rr % PPI; }
                    else          { img_e = bz; pos_e = bx*128 + rr; }
                    int oye = pos_e / HOUT, oxe = pos_e % HOUT;
                    float v = fmaxf(acc[mi][ni][rg] + b, 0.0f);
                    out[(((size_t)img_e * HOUT + oye) * HOUT + oxe) * COUT + oc] = __float2bfloat16(v);
                }
        }
    } else {
        int img_e = bz*IMGS + wm;
        #pragma unroll
        for (int ni = 0; ni < 4; ++ni) {
            int oc = nblk*128 + wn*64 + ni*16 + (lane & 15);
            float b = bias[oc];
            float s = 0.0f;
            #pragma unroll
            for (int mi = 0; mi < 4; ++mi)
                #pragma unroll
                for (int rg = 0; rg < 4; ++rg) s += fmaxf(acc[mi][ni][rg] + b, 0.0f);
            s += __shfl_xor(s, 16);
            s += __shfl_xor(s, 32);
            if (lane < 16)
                pooled[((size_t)(img0 + img_e))*256 + nblk*128 + wn*64 + ni*16 + lane] = s * (1.0f/64.0f);
        }
    }
}

// ---- fused: mean over C (commutes with linear FC) + FC 256->128 ----
__global__ void poolfc_kernel(const float* __restrict__ pooled, const float* __restrict__ Wfc,
                              const float* __restrict__ bfc, float* __restrict__ out) {
    int b = blockIdx.x;
    int t = threadIdx.x;
    __shared__ float pm[256];
    #pragma unroll
    for (int q = 0; q < 2; ++q) {
        int k = q*128 + t;
        float s = 0.0f;
        #pragma unroll
        for (int c = 0; c < kC; ++c) s += pooled[((size_t)(b*kC + c))*256 + k];
        pm[k] = s * (1.0f/kC);
    }
    __syncthreads();
    float acc = bfc[t];
    for (int k = 0; k < 256; ++k) acc = fmaf(pm[k], Wfc[(size_t)k*kLatent + t], acc);
    out[(size_t)b*kLatent + t] = acc;
}

extern "C" void kernel_launch(void* const* d_in, const int* in_sizes, int n_in,
                              void* d_out, int out_size, void* d_ws, size_t ws_size,
                              hipStream_t stream) {
    const float* x_raw = (const float*)d_in[0];
    const float* W1 = (const float*)d_in[1];  const float* b1 = (const float*)d_in[2];
    const float* W2 = (const float*)d_in[3];  const float* b2 = (const float*)d_in[4];
    const float* W3 = (const float*)d_in[5];  const float* b3 = (const float*)d_in[6];
    const float* W4 = (const float*)d_in[7];  const float* b4 = (const float*)d_in[8];
    const float* Wfc = (const float*)d_in[9]; const float* bfc = (const float*)d_in[10];
    float* out = (float*)d_out;

    char* wsb = (char*)d_ws;
    float* xn     = (float*)(wsb);                      // 256 KiB
    float* sq     = (float*)(wsb + (256u<<10));         // 256 KiB
    float* pooled = (float*)(wsb + (512u<<10));         // 512 KiB
    bf16* Wt2     = (bf16*)(wsb + (1280u<<10));         // 36 KiB
    bf16* Wt3     = (bf16*)(wsb + (1316u<<10));         // 144 KiB
    bf16* Wt4     = (bf16*)(wsb + (1460u<<10));         // 576 KiB
    bf16* W1b     = (bf16*)(wsb + (2036u<<10));         // 2 KiB
    bf16* zbuf    = (bf16*)(wsb + (2040u<<10));         // 1 KiB (zeroed below)
    char* chunk_base = wsb + (2048u<<10);               // 2 MiB header

    // per image: h2 NHWC (128 KiB) + h3 NHWC (64 KiB)
    const size_t perH2 = 32u*32u*64u*2u, perH3 = 16u*16u*128u*2u;
    const size_t perImg = perH2 + perH3;
    int chunk = 4;
    for (int c = 512; c >= 4; c >>= 1) {
        if ((2048u<<10) + (size_t)c * perImg <= ws_size) { chunk = c; break; }
    }

    hipMemsetAsync(zbuf, 0, 1024, stream);
    gaf_stats_kernel<<<kBC, kS, 0, stream>>>(x_raw, xn, sq);
    wtrans_all_kernel<<<(388096 + 255)/256, 256, 0, stream>>>(W1, W2, W3, W4, W1b, Wt2, Wt3, Wt4);

    for (int img0 = 0; img0 < kBC; img0 += chunk) {
        int nimg = chunk;
        bf16* h2 = (bf16*)chunk_base;
        bf16* h3 = (bf16*)(chunk_base + (size_t)chunk * perH2);

        // fused conv1+conv2: 2->32->64, 128->64->32
        conv12_kernel<<<dim3(8, nimg), 256, 0, stream>>>(xn, sq, W1b, b1, Wt2, b2, h2, img0);
        // conv3: 64->128, 32->16 : M=256/img -> 2 mblk, N=128 (one tile)
        conv_mfma_kernel<64, 128, 32, 1, false>
            <<<dim3(2, 1, nimg), 256, 0, stream>>>(h2, Wt3, b3, h3, nullptr, img0, zbuf);
        // conv4: 128->256, 16->8 : 2 imgs/block (M=128), N=256 -> 2 nblk, fused pool
        conv_mfma_kernel<128, 256, 16, 2, true>
            <<<dim3(1, 2, nimg/2), 256, 0, stream>>>(h3, Wt4, b4, nullptr, pooled, img0, zbuf);
    }

    poolfc_kernel<<<kB, kLatent, 0, stream>>>(pooled, Wfc, bfc, out);
}

// Round 17
// 207.252 us; speedup vs baseline: 1.5544x; 1.0346x over previous
//
#include <hip/hip_runtime.h>
#include <hip/hip_bf16.h>

#define DEV __device__ __forceinline__

constexpr int kB = 16, kC = 32, kT = 512, kS = 128, kBC = 512, kLatent = 128;
constexpr float kEps = 1e-8f;

using bf16 = __hip_bfloat16;
using bf16x8 = __attribute__((ext_vector_type(8))) short;
using f32x4  = __attribute__((ext_vector_type(4))) float;

DEV unsigned short f2bf(float v) {
    bf16 h = __float2bfloat16(v);
    return *(unsigned short*)&h;
}

DEV void gld16(const void* g, void* l) {
    __builtin_amdgcn_global_load_lds(
        (const __attribute__((address_space(1))) unsigned*)g,
        (__attribute__((address_space(3))) unsigned*)l, 16, 0, 0);
}

// ---- fused prep: per-(b,c) stats (blocks 0..511) + all weight transposes ----
__global__ void prep_kernel(const float* __restrict__ x_raw,
                            const float* __restrict__ w1, const float* __restrict__ w2,
                            const float* __restrict__ w3, const float* __restrict__ w4,
                            float* __restrict__ xn, float* __restrict__ sq,
                            bf16* __restrict__ w1b, bf16* __restrict__ wt2,
                            bf16* __restrict__ wt3, bf16* __restrict__ wt4) {
    int tid = threadIdx.x;
    if (blockIdx.x < 512) {
        __shared__ float smn[kS], smx[kS];
        int bc = blockIdx.x;
        float v = 0.0f;
        if (tid < 128) {
            const float* xp = x_raw + (size_t)bc * kT;
            v = 0.25f * (xp[4*tid] + xp[4*tid+1] + xp[4*tid+2] + xp[4*tid+3]);
            smn[tid] = v; smx[tid] = v;
        }
        __syncthreads();
        for (int off = kS/2; off > 0; off >>= 1) {
            if (tid < off) {
                smn[tid] = fminf(smn[tid], smn[tid+off]);
                smx[tid] = fmaxf(smx[tid], smx[tid+off]);
            }
            __syncthreads();
        }
        if (tid < 128) {
            float mn = smn[0], mx = smx[0];
            float xv = 2.0f * (v - mn) / (mx - mn + kEps) - 1.0f;
            xv = fminf(fmaxf(xv, -1.0f), 1.0f);
            float sv = sqrtf(fminf(fmaxf(1.0f - xv*xv, 0.0f), 1.0f));
            xn[bc*kS + tid] = xv;
            sq[bc*kS + tid] = sv;
        }
        return;
    }
    int idx = (blockIdx.x - 512) * blockDim.x + tid;
    if (idx < 1024) {
        int oc = idx >> 5, k = idx & 31;
        w1b[idx] = __float2bfloat16(k < 18 ? w1[oc*18 + k] : 0.0f);
        return;
    }
    idx -= 1024;
    const float* src; bf16* dst; int CIN, COUT;
    if (idx < 18432)       { src = w2; dst = wt2; CIN = 32;  COUT = 64;  }
    else if (idx < 92160)  { idx -= 18432;  src = w3; dst = wt3; CIN = 64;  COUT = 128; }
    else if (idx < 387072) { idx -= 92160;  src = w4; dst = wt4; CIN = 128; COUT = 256; }
    else return;
    int ic = idx % CIN;
    int oc = (idx / CIN) % COUT;
    int t  = idx / (CIN * COUT);
    dst[((size_t)t * COUT + oc) * CIN + ic] = __float2bfloat16(src[((size_t)oc * CIN + ic) * 9 + t]);
}

// ---- FUSED conv1+conv2 (round-16 structure; packed bf16 cvt in phase 1a) ----
__global__ __launch_bounds__(256, 4)
void conv12_kernel(const float* __restrict__ xn, const float* __restrict__ sq,
                   const bf16* __restrict__ w1b, const float* __restrict__ b1,
                   const bf16* __restrict__ wt2, const float* __restrict__ b2,
                   bf16* __restrict__ out, int img0) {
    __shared__ float xl[kS], sl[kS];
    __shared__ __align__(16) short GH[18432];    // 36 KiB: G[576][4][8] / H[2][288][4][8]
    __shared__ __align__(16) short W1s[32][40];  // 2.5 KiB

    int tid  = threadIdx.x;
    int lane = tid & 63;
    int wv   = tid >> 6;
    int mblk = blockIdx.x;
    int bz   = blockIdx.y;
    int bc   = img0 + bz;

    if (tid < 128) {
        xl[tid] = xn[(size_t)bc * kS + tid];
        int rr = tid >> 2, sg = tid & 3;
        *(uint4*)&W1s[rr][sg*8] = *(const uint4*)(w1b + rr*32 + sg*8);
    } else {
        sl[tid - 128] = sq[(size_t)bc * kS + (tid - 128)];
    }
    __syncthreads();

    // ---- Phase 1a: G (swizzled slots, packed cvt) ----
    #pragma unroll
    for (int it = 0; it < 3; ++it) {
        int idx = it * 256 + tid;
        if (idx >= 576) break;
        int trow = idx >> 6, hx = idx & 63;
        int iy = 8 * mblk + trow;
        unsigned int pk[16];
        #pragma unroll
        for (int j = 0; j < 16; ++j) pk[j] = 0u;
        if (iy < 64) {
            float xr[3], sr[3], xc[3], sc[3];
            #pragma unroll
            for (int k = 0; k < 3; ++k) {
                int iyy = 2*iy + k, ixx = 2*hx + k;
                bool vy = iyy < kS, vx = ixx < kS;
                xr[k] = vy ? xl[iyy] : 0.0f;  sr[k] = vy ? sl[iyy] : 0.0f;
                xc[k] = vx ? xl[ixx] : 0.0f;  sc[k] = vx ? sl[ixx] : 0.0f;
            }
            float fg[18];
            #pragma unroll
            for (int ky = 0; ky < 3; ++ky)
                #pragma unroll
                for (int kx = 0; kx < 3; ++kx) {
                    fg[ky*3+kx]   = xr[ky]*xc[kx] - sr[ky]*sc[kx];   // gasf
                    fg[9+ky*3+kx] = sr[ky]*xc[kx] - xr[ky]*sc[kx];   // gadf
                }
            #pragma unroll
            for (int j = 0; j < 9; ++j) {
                __hip_bfloat162 hh = __float22bfloat162_rn(make_float2(fg[2*j], fg[2*j+1]));
                pk[j] = *(unsigned int*)&hh;
            }
        }
        #pragma unroll
        for (int j = 0; j < 4; ++j)
            *(uint4*)&GH[idx*32 + ((j ^ (idx & 3)) * 8)] = ((uint4*)pk)[j];
    }
    __syncthreads();

    // ---- Phase 1b: h1 = relu(G @ W1b^T + b1) ----
    f32x4 c1[9][2];
    bf16x8 w1f0 = *(const bf16x8*)&W1s[(lane & 15)][(lane>>4)*8];
    bf16x8 w1f1 = *(const bf16x8*)&W1s[16 + (lane & 15)][(lane>>4)*8];
    #pragma unroll
    for (int j = 0; j < 9; ++j) {
        int mt = 4*j + wv;
        int row = mt*16 + (lane & 15);
        bf16x8 af = *(const bf16x8*)&GH[row*32 + (((lane>>4) ^ (row & 3)) * 8)];
        f32x4 zz = f32x4{0.f, 0.f, 0.f, 0.f};
        c1[j][0] = __builtin_amdgcn_mfma_f32_16x16x32_bf16(af, w1f0, zz, 0, 0, 0);
        c1[j][1] = __builtin_amdgcn_mfma_f32_16x16x32_bf16(af, w1f1, zz, 0, 0, 0);
    }
    __syncthreads();   // all G reads complete before overwrite

    #pragma unroll
    for (int j = 0; j < 9; ++j) {
        int mt = 4*j + wv;
        #pragma unroll
        for (int h = 0; h < 2; ++h) {
            int oc = h*16 + (lane & 15);
            float bb = b1[oc];
            #pragma unroll
            for (int rg = 0; rg < 4; ++rg) {
                int pos = mt*16 + (lane>>4)*4 + rg;
                int trow = pos >> 6, hx = pos & 63;
                int par = hx & 1, col = hx >> 1;
                int r = trow*32 + col;
                float v = fmaxf(c1[j][h][rg] + bb, 0.0f);
                if (8*mblk + trow >= 64) v = 0.0f;   // SAME padding row
                GH[par*9216 + r*32 + (((oc>>3) ^ (r & 3)) * 8) + (oc & 7)] = (short)f2bf(v);
            }
        }
    }
    __syncthreads();

    // ---- Phase 2: conv2 GEMM, barrier-free (B direct from global) ----
    auto loadB2 = [&](int tap, bf16x8* dst) {
        #pragma unroll
        for (int ni = 0; ni < 4; ++ni) {
            int row = ni*16 + (lane & 15);
            dst[ni] = *(const bf16x8*)(wt2 + ((size_t)tap*64 + row)*32 + (lane>>4)*8);
        }
    };
    f32x4 acc[2][4];
    #pragma unroll
    for (int i = 0; i < 2; ++i)
        #pragma unroll
        for (int j = 0; j < 4; ++j) acc[i][j] = f32x4{0.f, 0.f, 0.f, 0.f};

    bf16x8 bcur[4], bnxt[4];
    loadB2(0, bcur);
    for (int tap = 0; tap < 9; ++tap) {
        if (tap + 1 < 9) loadB2(tap + 1, bnxt);
        int ky = tap / 3, kx = tap % 3;
        int trow = 2*wv + ky;
        bf16x8 af[2];
        #pragma unroll
        for (int mi = 0; mi < 2; ++mi) {
            int ocol = mi*16 + (lane & 15);
            int x = 2*ocol + kx;
            int par = x & 1;
            int col = x >> 1; if (col > 31) col = 31;
            int r = trow*32 + col;
            bf16x8 v = *(const bf16x8*)&GH[par*9216 + r*32 + (((lane>>4) ^ (r & 3)) * 8)];
            bf16x8 z = {0,0,0,0,0,0,0,0};
            af[mi] = (x < 64) ? v : z;
        }
        #pragma unroll
        for (int mi = 0; mi < 2; ++mi)
            #pragma unroll
            for (int ni = 0; ni < 4; ++ni)
                acc[mi][ni] = __builtin_amdgcn_mfma_f32_16x16x32_bf16(af[mi], bcur[ni], acc[mi][ni], 0, 0, 0);
        #pragma unroll
        for (int ni = 0; ni < 4; ++ni) bcur[ni] = bnxt[ni];
    }

    int oy = 4*mblk + wv;
    #pragma unroll
    for (int ni = 0; ni < 4; ++ni) {
        int oc = ni*16 + (lane & 15);
        float b = b2[oc];
        #pragma unroll
        for (int mi = 0; mi < 2; ++mi)
            #pragma unroll
            for (int rg = 0; rg < 4; ++rg) {
                int ocol = 16*mi + (lane>>4)*4 + rg;
                float v = fmaxf(acc[mi][ni][rg] + b, 0.0f);
                out[(((size_t)bz*32 + oy)*32 + ocol)*64 + oc] = __float2bfloat16(v);
            }
    }
}

// ---- MFMA implicit-GEMM conv (gld16 streaming, IC-MAJOR K, KU-unrolled) ----
// Block 128M x 128N, 2x2 waves (wave 64x64, acc 4x4), KU 32-K slices per LDS
// buffer (double-buffered), 1 barrier per KU slices. ic-major K: taps innermost
// re-read the same pixel window -> L1/L2-hot re-stages.
template<int CIN, int COUT, int HIN, int IMGS, int KU, bool POOL>
__global__ __launch_bounds__(256, 4)
void conv_mfma_kernel(const bf16* __restrict__ in, const bf16* __restrict__ wt,
                      const float* __restrict__ bias, bf16* __restrict__ out,
                      float* __restrict__ pooled, int img0,
                      const bf16* __restrict__ zbuf) {
    constexpr int HOUT = HIN / 2;
    constexpr int PPI  = HOUT * HOUT;
    constexpr int S32  = 9 * (CIN / 32);
    constexpr int SO   = S32 / KU;
    __shared__ __align__(16) short As[2*128*32*KU];
    __shared__ __align__(16) short Bs[2*128*32*KU];

    int tid  = threadIdx.x;
    int lane = tid & 63;
    int wv   = tid >> 6;
    int wm   = wv >> 1, wn = wv & 1;
    int bx   = blockIdx.x;
    int nblk = blockIdx.y;
    int bz   = blockIdx.z;

    int rsub = lane >> 2, seg = lane & 3;
    int imgA[2], oyA[2], oxA[2], rB[2];
    #pragma unroll
    for (int j = 0; j < 2; ++j) {
        int r = (wv*2 + j)*16 + rsub;       // 0..127
        int il, pos;
        if (IMGS > 1) { il = bz*IMGS + r/PPI; pos = r % PPI; }
        else          { il = bz; pos = bx*128 + r; }
        imgA[j] = il; oyA[j] = pos / HOUT; oxA[j] = pos % HOUT;
        rB[j] = r;
    }

    auto issue = [&](int so, int nb) {
        #pragma unroll
        for (int u = 0; u < KU; ++u) {
            int s = so*KU + u;
            int icb = (s / 9) * 32;            // ic-major
            int tap = s % 9;                   // taps innermost -> window reuse
            int ky = tap / 3, kx = tap % 3;
            #pragma unroll
            for (int j = 0; j < 2; ++j) {
                int iy = 2*oyA[j] + ky, ix = 2*oxA[j] + kx;
                const bf16* ga = (iy < HIN && ix < HIN)
                    ? in + (((size_t)imgA[j]*HIN + iy)*HIN + ix)*CIN + icb + seg*8
                    : zbuf + seg*8;
                gld16(ga, (char*)As + (nb*KU + u)*8192 + (wv*2 + j)*1024 + lane*16);
                const bf16* gb = wt + ((size_t)tap*COUT + nblk*128 + rB[j])*CIN + icb + seg*8;
                gld16(gb, (char*)Bs + (nb*KU + u)*8192 + (wv*2 + j)*1024 + lane*16);
            }
        }
    };

    f32x4 acc[4][4];
    #pragma unroll
    for (int i = 0; i < 4; ++i)
        #pragma unroll
        for (int j = 0; j < 4; ++j) acc[i][j] = f32x4{0.f, 0.f, 0.f, 0.f};

    issue(0, 0);
    __syncthreads();

    for (int so = 0; so < SO; ++so) {
        int cur = so & 1;
        if (so + 1 < SO) issue(so + 1, cur ^ 1);
        #pragma unroll
        for (int u = 0; u < KU; ++u) {
            bf16x8 af[4], bfr[4];
            #pragma unroll
            for (int mi = 0; mi < 4; ++mi)
                af[mi] = *(const bf16x8*)&As[(cur*KU + u)*4096 + (wm*64 + mi*16 + (lane&15))*32 + (lane>>4)*8];
            #pragma unroll
            for (int ni = 0; ni < 4; ++ni)
                bfr[ni] = *(const bf16x8*)&Bs[(cur*KU + u)*4096 + (wn*64 + ni*16 + (lane&15))*32 + (lane>>4)*8];
            #pragma unroll
            for (int mi = 0; mi < 4; ++mi)
                #pragma unroll
                for (int ni = 0; ni < 4; ++ni)
                    acc[mi][ni] = __builtin_amdgcn_mfma_f32_16x16x32_bf16(af[mi], bfr[ni], acc[mi][ni], 0, 0, 0);
        }
        __syncthreads();
    }

    if (!POOL) {
        #pragma unroll
        for (int ni = 0; ni < 4; ++ni) {
            int oc = nblk*128 + wn*64 + ni*16 + (lane & 15);
            float b = bias[oc];
            #pragma unroll
            for (int mi = 0; mi < 4; ++mi)
                #pragma unroll
                for (int rg = 0; rg < 4; ++rg) {
                    int rr = wm*64 + mi*16 + (lane>>4)*4 + rg;
                    int img_e, pos_e;
                    if (IMGS > 1) { img_e = bz*IMGS + rr/PPI; pos_e = rr % PPI; }
                    else          { img_e = bz; pos_e = bx*128 + rr; }
                    int oye = pos_e / HOUT, oxe = pos_e % HOUT;
                    float v = fmaxf(acc[mi][ni][rg] + b, 0.0f);
                    out[(((size_t)img_e * HOUT + oye) * HOUT + oxe) * COUT + oc] = __float2bfloat16(v);
                }
        }
    } else {
        int img_e = bz*IMGS + wm;
        #pragma unroll
        for (int ni = 0; ni < 4; ++ni) {
            int oc = nblk*128 + wn*64 + ni*16 + (lane & 15);
            float b = bias[oc];
            float s = 0.0f;
            #pragma unroll
            for (int mi = 0; mi < 4; ++mi)
                #pragma unroll
                for (int rg = 0; rg < 4; ++rg) s += fmaxf(acc[mi][ni][rg] + b, 0.0f);
            s += __shfl_xor(s, 16);
            s += __shfl_xor(s, 32);
            if (lane < 16)
                pooled[((size_t)(img0 + img_e))*256 + nblk*128 + wn*64 + ni*16 + lane] = s * (1.0f/64.0f);
        }
    }
}

// ---- fused: mean over C (commutes with linear FC) + FC 256->128 ----
__global__ void poolfc_kernel(const float* __restrict__ pooled, const float* __restrict__ Wfc,
                              const float* __restrict__ bfc, float* __restrict__ out) {
    int b = blockIdx.x;
    int t = threadIdx.x;
    __shared__ float pm[256];
    #pragma unroll
    for (int q = 0; q < 2; ++q) {
        int k = q*128 + t;
        float s = 0.0f;
        #pragma unroll
        for (int c = 0; c < kC; ++c) s += pooled[((size_t)(b*kC + c))*256 + k];
        pm[k] = s * (1.0f/kC);
    }
    __syncthreads();
    float acc = bfc[t];
    for (int k = 0; k < 256; ++k) acc = fmaf(pm[k], Wfc[(size_t)k*kLatent + t], acc);
    out[(size_t)b*kLatent + t] = acc;
}

extern "C" void kernel_launch(void* const* d_in, const int* in_sizes, int n_in,
                              void* d_out, int out_size, void* d_ws, size_t ws_size,
                              hipStream_t stream) {
    const float* x_raw = (const float*)d_in[0];
    const float* W1 = (const float*)d_in[1];  const float* b1 = (const float*)d_in[2];
    const float* W2 = (const float*)d_in[3];  const float* b2 = (const float*)d_in[4];
    const float* W3 = (const float*)d_in[5];  const float* b3 = (const float*)d_in[6];
    const float* W4 = (const float*)d_in[7];  const float* b4 = (const float*)d_in[8];
    const float* Wfc = (const float*)d_in[9]; const float* bfc = (const float*)d_in[10];
    float* out = (float*)d_out;

    char* wsb = (char*)d_ws;
    float* xn     = (float*)(wsb);                      // 256 KiB
    float* sq     = (float*)(wsb + (256u<<10));         // 256 KiB
    float* pooled = (float*)(wsb + (512u<<10));         // 512 KiB
    bf16* Wt2     = (bf16*)(wsb + (1280u<<10));         // 36 KiB
    bf16* Wt3     = (bf16*)(wsb + (1316u<<10));         // 144 KiB
    bf16* Wt4     = (bf16*)(wsb + (1460u<<10));         // 576 KiB
    bf16* W1b     = (bf16*)(wsb + (2036u<<10));         // 2 KiB
    bf16* zbuf    = (bf16*)(wsb + (2040u<<10));         // 1 KiB (zeroed below)
    char* chunk_base = wsb + (2048u<<10);               // 2 MiB header

    // per image: h2 NHWC (128 KiB) + h3 NHWC (64 KiB)
    const size_t perH2 = 32u*32u*64u*2u, perH3 = 16u*16u*128u*2u;
    const size_t perImg = perH2 + perH3;
    int chunk = 4;
    for (int c = 512; c >= 4; c >>= 1) {
        if ((2048u<<10) + (size_t)c * perImg <= ws_size) { chunk = c; break; }
    }

    hipMemsetAsync(zbuf, 0, 1024, stream);
    prep_kernel<<<512 + (388096 + 255)/256, 256, 0, stream>>>(
        x_raw, W1, W2, W3, W4, xn, sq, W1b, Wt2, Wt3, Wt4);

    for (int img0 = 0; img0 < kBC; img0 += chunk) {
        int nimg = chunk;
        bf16* h2 = (bf16*)chunk_base;
        bf16* h3 = (bf16*)(chunk_base + (size_t)chunk * perH2);

        // fused conv1+conv2: 2->32->64, 128->64->32
        conv12_kernel<<<dim3(8, nimg), 256, 0, stream>>>(xn, sq, W1b, b1, Wt2, b2, h2, img0);
        // conv3: 64->128, 32->16 : KU=1 (32 KiB LDS, 4 blocks/CU)
        conv_mfma_kernel<64, 128, 32, 1, 1, false>
            <<<dim3(2, 1, nimg), 256, 0, stream>>>(h2, Wt3, b3, h3, nullptr, img0, zbuf);
        // conv4: 128->256, 16->8 : KU=2 (64 KiB LDS, 18 barriers), fused pool
        conv_mfma_kernel<128, 256, 16, 2, 2, true>
            <<<dim3(1, 2, nimg/2), 256, 0, stream>>>(h3, Wt4, b4, nullptr, pooled, img0, zbuf);
    }

    poolfc_kernel<<<kB, kLatent, 0, stream>>>(pooled, Wfc, bfc, out);
}